// Round 8
// baseline (202.418 us; speedup 1.0000x reference)
//
#include <hip/hip_runtime.h>

#define SEQ 2048
#define NH 16
#define HD 64
#define DMODEL 1024

__device__ __forceinline__ unsigned int f2bf(float f) {
  // fp32 -> bf16 bits, round-to-nearest-even (finite inputs only)
  unsigned int u = __float_as_uint(f);
  return ((u + 0x7fffu + ((u >> 16) & 1u)) >> 16) & 0xffffu;
}

// packed fp32x2 -> bf16x2 (RNE via __bf16 cvt)
__device__ __forceinline__ unsigned int pk2bf(float a, float b) {
  unsigned short ua = __builtin_bit_cast(unsigned short, (__bf16)a);
  unsigned short ub = __builtin_bit_cast(unsigned short, (__bf16)b);
  return (unsigned int)ua | ((unsigned int)ub << 16);
}

typedef __bf16 bf16x8 __attribute__((ext_vector_type(8)));
typedef float f32x4 __attribute__((ext_vector_type(4)));
typedef unsigned int uix4 __attribute__((ext_vector_type(4)));
typedef unsigned int uix2 __attribute__((ext_vector_type(2)));

// async global->LDS, 16B per lane; LDS dest = wave-uniform base + lane*16
__device__ __forceinline__ void gl2lds16(const unsigned short* g, unsigned short* l) {
  __builtin_amdgcn_global_load_lds(
      (const __attribute__((address_space(1))) unsigned int*)g,
      (__attribute__((address_space(3))) unsigned int*)l, 16, 0, 0);
}

// one launch casts x + all four weight matrices to bf16
__global__ __launch_bounds__(256) void cast_all_kernel(
    const float* __restrict__ x, const float* __restrict__ wq,
    const float* __restrict__ wk, const float* __restrict__ wv,
    const float* __restrict__ wo,
    unsigned short* __restrict__ xb, unsigned short* __restrict__ wqb,
    unsigned short* __restrict__ wkb, unsigned short* __restrict__ wvb,
    unsigned short* __restrict__ wob) {
  int idx = blockIdx.x * 256 + threadIdx.x;
  if (idx >= 1048576) return;
  const float* src;
  unsigned short* dst;
  int off;
  if (idx < 524288) {
    src = x; dst = xb; off = idx;
  } else {
    int t = idx - 524288;
    int w = t >> 17;
    off = t & 131071;
    src = (w == 0) ? wq : (w == 1) ? wk : (w == 2) ? wv : wo;
    dst = (w == 0) ? wqb : (w == 1) ? wkb : (w == 2) ? wvb : wob;
  }
  const float4* p = reinterpret_cast<const float4*>(src) + (size_t)off * 2;
  float4 a = p[0], b = p[1];
  uint4 o;
  o.x = f2bf(a.x) | (f2bf(a.y) << 16);
  o.y = f2bf(a.z) | (f2bf(a.w) << 16);
  o.z = f2bf(b.x) | (f2bf(b.y) << 16);
  o.w = f2bf(b.z) | (f2bf(b.w) << 16);
  reinterpret_cast<uint4*>(dst)[off] = o;
}

// TM x 128-tile GEMM, BK=64, global_load_lds staging, XOR-swizzled LDS chunks.
// Double-buffered LDS, ONE barrier per K-step. Natural blockIdx mapping
// (T1 XCD swizzle REVERTED: round-7 measured FETCH 41->54 MB, dur +10 us --
// each XCD streamed the full 6 MB B panel; and the GEMM is schedule-bound,
// not BW-bound, so L2 locality isn't the lever here. ERRATA r7.)
// MODE 0: fused QKV epilogue; MODE 1: fp32 C + bias (out projection).
template <int MODE, int TM>
__global__ __launch_bounds__(256) void gemm128(
    const unsigned short* __restrict__ A, const unsigned short* __restrict__ B,
    const float* __restrict__ bias0, const float* __restrict__ bias1,
    const float* __restrict__ bias2, float* __restrict__ Cf,
    unsigned short* __restrict__ Qo, unsigned short* __restrict__ Ko,
    unsigned short* __restrict__ Vto, int Kdim) {
  constexpr int MT = TM / 32;  // acc rows (16-row frags) per wave
  __shared__ __align__(16) unsigned short As[2][TM * 64];
  __shared__ __align__(16) unsigned short Bs[2][128 * 64];
  const int tid = threadIdx.x;
  const int wave = tid >> 6, lane = tid & 63;
  const int wm = wave >> 1, wn = wave & 1;  // 2x2 waves
  const int fr = lane & 15, quad = lane >> 4;
  const int fx = fr & 7;  // swizzle key for fragment reads
  const int n0 = blockIdx.x * 128, m0 = blockIdx.y * TM;

  // staging: lane -> (row = lane>>3, swizzled chunk = (lane&7) ^ ((lane>>3)&7))
  const int srowg = lane >> 3;
  const int schunk = (lane & 7) ^ (srowg & 7);
  const unsigned short* Abase =
      A + (size_t)(m0 + wave * (TM / 4) + srowg) * Kdim + schunk * 8;
  const unsigned short* Bbase =
      B + (size_t)(n0 + wave * 32 + srowg) * Kdim + schunk * 8;
  const int awoff = (wave * (TM / 4)) * 64;
  const int bwoff = (wave * 32) * 64;

  f32x4 acc[MT][4];
#pragma unroll
  for (int mt = 0; mt < MT; ++mt)
#pragma unroll
    for (int nt = 0; nt < 4; ++nt) acc[mt][nt] = f32x4{0.f, 0.f, 0.f, 0.f};

  // prologue: stage K-tile 0 into buffer 0
#pragma unroll
  for (int t = 0; t < TM / 32; ++t)
    gl2lds16(Abase + (size_t)(t * 8) * Kdim, As[0] + awoff + t * 8 * 64);
#pragma unroll
  for (int t = 0; t < 4; ++t)
    gl2lds16(Bbase + (size_t)(t * 8) * Kdim, Bs[0] + bwoff + t * 8 * 64);

  const int nk = Kdim >> 6;
  for (int kk = 0; kk < nk; ++kk) {
    __syncthreads();   // drains DMA[kk] (vmcnt) + guards buffer reuse
    if (kk + 1 < nk) { // prefetch next K-tile into the other buffer
      const int k0n = (kk + 1) * 64;
      unsigned short* An = As[(kk + 1) & 1] + awoff;
      unsigned short* Bn = Bs[(kk + 1) & 1] + bwoff;
#pragma unroll
      for (int t = 0; t < TM / 32; ++t)
        gl2lds16(Abase + (size_t)(t * 8) * Kdim + k0n, An + t * 8 * 64);
#pragma unroll
      for (int t = 0; t < 4; ++t)
        gl2lds16(Bbase + (size_t)(t * 8) * Kdim + k0n, Bn + t * 8 * 64);
    }
    const unsigned short* Acur = As[kk & 1];
    const unsigned short* Bcur = Bs[kk & 1];
#pragma unroll
    for (int ks = 0; ks < 2; ++ks) {
      bf16x8 af[MT], bfv[4];
#pragma unroll
      for (int mt = 0; mt < MT; ++mt)
        af[mt] = *reinterpret_cast<const bf16x8*>(
            Acur + (wm * (TM / 2) + mt * 16 + fr) * 64 + ((ks * 4 + quad) ^ fx) * 8);
#pragma unroll
      for (int nt = 0; nt < 4; ++nt)
        bfv[nt] = *reinterpret_cast<const bf16x8*>(
            Bcur + (wn * 64 + nt * 16 + fr) * 64 + ((ks * 4 + quad) ^ fx) * 8);
#pragma unroll
      for (int mt = 0; mt < MT; ++mt)
#pragma unroll
        for (int nt = 0; nt < 4; ++nt)
          acc[mt][nt] = __builtin_amdgcn_mfma_f32_16x16x32_bf16(
              af[mt], bfv[nt], acc[mt][nt], 0, 0, 0);
    }
  }

  // epilogue. C/D: col = lane&15, row = quad*4+reg (m89/m91-verified).
  if (MODE == 0) {
    const int seg = n0 >> 10;  // uniform per block
    const float* bp = (seg == 0) ? bias0 : (seg == 1) ? bias1 : bias2;
    // Q pre-scaled by (1/sqrt(64)) * log2(e): attention works in exp2 domain
    const float scale = (seg == 0) ? 0.1803368809f : 1.0f;
    unsigned short* QK = (seg == 0) ? Qo : Ko;
#pragma unroll
    for (int nt = 0; nt < 4; ++nt) {
      const int c = (n0 + wn * 64 + nt * 16 + fr) & 1023;
      const int h = c >> 6, d = c & 63;
      const float bs = bp[c];
#pragma unroll
      for (int mt = 0; mt < MT; ++mt) {
        const int mbase = m0 + wm * (TM / 2) + mt * 16 + quad * 4;
        const int b = mbase >> 11, s0 = mbase & 2047;
        if (seg < 2) {
          unsigned short* dst = QK + (((size_t)(b * NH + h)) * SEQ + s0) * HD + d;
#pragma unroll
          for (int r = 0; r < 4; ++r)
            dst[(size_t)r * HD] = (unsigned short)f2bf((acc[mt][nt][r] + bs) * scale);
        } else {  // V^T: rows contiguous in s -> 8B store
          uint2 pk;
          pk.x = pk2bf(acc[mt][nt][0] + bs, acc[mt][nt][1] + bs);
          pk.y = pk2bf(acc[mt][nt][2] + bs, acc[mt][nt][3] + bs);
          *reinterpret_cast<uint2*>(
              Vto + (((size_t)(b * NH + h)) * HD + d) * SEQ + s0) = pk;
        }
      }
    }
  } else {
#pragma unroll
    for (int nt = 0; nt < 4; ++nt) {
      const int cg = n0 + wn * 64 + nt * 16 + fr;
      const float bs = bias0[cg];
#pragma unroll
      for (int mt = 0; mt < MT; ++mt) {
        const int mbase = m0 + wm * (TM / 2) + mt * 16 + quad * 4;
#pragma unroll
        for (int r = 0; r < 4; ++r)
          Cf[(size_t)(mbase + r) * DMODEL + cg] = acc[mt][nt][r] + bs;
      }
    }
  }
}

// ---------------------------------------------------------------------------
// ROUND 8: flash-decoding split for the causal tail.
// Diagnosis: 1024 blocks = exactly 4/CU resident, NO refill; time-average
// occupancy 27% ~= avg(chain)/max(chain) = 16.5/32 -- the machine idles in
// the tail while ib=31's 32-pass chain finishes. Class balance fixed SUMS,
// not makespans.
// Fix: ib >= 20 is computed by TWO blocks (j-halves) writing partial
// (o, m, l) f32 to workspace; attn_combine merges. Max chain 32 -> 20.
// Grid 1408 = 44 units x 32 bh, unit table ordered LONGEST-FIRST (LPT) so
// long chains start immediately; 5 blocks/CU resident (LDS 32 KB) + refill.
// Unit u -> (ib, jlo, jhi, half): half<0 = unsplit (direct cb write).
// ---------------------------------------------------------------------------
__device__ const int ATT_IB[44] = {19,18,17,16,15,30,31,31,14,28,29,29,30,13,26,27,27,28,12,24,25,25,26,11,22,23,23,24,10,20,21,21,22, 9,20, 8, 7, 6, 5, 4, 3, 2, 1, 0};
__device__ const int ATT_LO[44] = { 0, 0, 0, 0, 0, 0, 0,16, 0, 0, 0,15,16, 0, 0, 0,14,15, 0, 0, 0,13,14, 0, 0, 0,12,13, 0, 0, 0,11,12, 0,11, 0, 0, 0, 0, 0, 0, 0, 0, 0};
__device__ const int ATT_HI[44] = {19,18,17,16,15,15,15,31,14,14,14,29,30,13,13,13,27,28,12,12,12,25,26,11,11,11,23,24,10,10,10,21,22, 9,20, 8, 7, 6, 5, 4, 3, 2, 1, 0};
__device__ const int ATT_HF[44] = {-1,-1,-1,-1,-1, 0, 0, 1,-1, 0, 0, 1, 1,-1, 0, 0, 1, 1,-1, 0, 0, 1, 1,-1, 0, 0, 1, 1,-1, 0, 0, 1, 1,-1, 1,-1,-1,-1,-1,-1,-1,-1,-1,-1};

__global__ __launch_bounds__(256, 5) void attn_mfma_kernel(
    const unsigned short* __restrict__ Qg, const unsigned short* __restrict__ Kg,
    const unsigned short* __restrict__ Vtg, const int* __restrict__ mask,
    unsigned short* __restrict__ concat,
    float* __restrict__ part_o, float* __restrict__ part_ml) {
  const int u = blockIdx.x >> 5;
  const int bh = blockIdx.x & 31;
  const int ib = ATT_IB[u], jlo = ATT_LO[u], jhi = ATT_HI[u], hf = ATT_HF[u];
  const int b = bh >> 4, h = bh & 15;
  const int tid = threadIdx.x;
  const int wave = tid >> 6, lane = tid & 63;
  const int quad = lane >> 4, fr = lane & 15;
  const int fx = fr & 7;

  __shared__ __align__(16) unsigned short Ks[2][64 * 64];   // swizzled, pi-permuted rows
  __shared__ __align__(16) unsigned short Vts[2][64 * 64];  // swizzled, pitch 64

  const unsigned short* Qb = Qg + ((size_t)bh * SEQ) * HD;
  const unsigned short* Kb = Kg + ((size_t)bh * SEQ) * HD;
  const unsigned short* Vtb = Vtg + ((size_t)bh * HD) * SEQ;
  const int* maskb = mask + b * SEQ;

  bool badl = false;
  {
    const int4* mp4 = reinterpret_cast<const int4*>(maskb);
#pragma unroll
    for (int uu = 0; uu < 8; ++uu) {
      int4 v = mp4[lane * 8 + uu];
      badl |= !(v.x && v.y && v.z && v.w);
    }
  }
  const unsigned long long bm = __ballot(badl);

  const int ir = ib * 64 + wave * 16 + fr;  // this lane's Q row (softmax owner)
  const bf16x8 q0 = *reinterpret_cast<const bf16x8*>(Qb + (size_t)ir * HD + quad * 8);
  const bf16x8 q1 = *reinterpret_cast<const bf16x8*>(Qb + (size_t)ir * HD + quad * 8 + 32);
  const int padi = maskb[ir];

  f32x4 o[4];
#pragma unroll
  for (int vt = 0; vt < 4; ++vt) o[vt] = f32x4{0.f, 0.f, 0.f, 0.f};
  float mr = -1e20f;
  float lq = 0.f;

  const int srow8 = lane >> 3;
  const int sch8 = (lane & 7) ^ (srow8 & 7);
  const int kprow = (wave >> 1) * 32 + ((srow8 >> 2)) * 8 + (wave & 1) * 4 + (srow8 & 3);
  const unsigned short* Kcol = Kb + sch8 * 8;
  const unsigned short* Vsrc = Vtb + (size_t)(wave * 16 + srow8) * SEQ + sch8 * 8;
  const int cA0 = (quad ^ fx) * 8;
  const int cA1 = ((quad + 4) ^ fx) * 8;

  {  // pre-issue DMA for jc=jlo into buffer (jlo&1)
    const int jl64 = jlo * 64;
    unsigned short* KsW = Ks[jlo & 1] + (wave * 16) * 64;
    unsigned short* VtsW = Vts[jlo & 1] + (wave * 16) * 64;
#pragma unroll
    for (int t = 0; t < 2; ++t) {
      gl2lds16(Kcol + (size_t)(jl64 + kprow + t * 16) * HD, KsW + t * 8 * 64);
      gl2lds16(Vsrc + (size_t)(t * 8) * SEQ + jl64, VtsW + t * 8 * 64);
    }
  }

  for (int jc = jlo; jc <= jhi; ++jc) {
    __syncthreads();
    if (jc < jhi) {
      const int jn = (jc + 1) * 64;
      unsigned short* KsW = Ks[(jc + 1) & 1] + (wave * 16) * 64;
      unsigned short* VtsW = Vts[(jc + 1) & 1] + (wave * 16) * 64;
#pragma unroll
      for (int t = 0; t < 2; ++t) {
        gl2lds16(Kcol + (size_t)(jn + kprow + t * 16) * HD, KsW + t * 8 * 64);
        gl2lds16(Vsrc + (size_t)(t * 8) * SEQ + jn, VtsW + t * 8 * 64);
      }
    }
    const unsigned short* Kcur = Ks[jc & 1];
    const unsigned short* Vcur = Vts[jc & 1];
    const int j0 = jc * 64;
    const bool tb = ((bm >> (2 * jc)) & 3ull) != 0ull;

    f32x4 st[4];
    __builtin_amdgcn_s_setprio(1);
#pragma unroll
    for (int jt = 0; jt < 4; ++jt) {
      bf16x8 ka0 = *reinterpret_cast<const bf16x8*>(&Kcur[(jt * 16 + fr) * 64 + cA0]);
      bf16x8 ka1 = *reinterpret_cast<const bf16x8*>(&Kcur[(jt * 16 + fr) * 64 + cA1]);
      st[jt] = f32x4{0.f, 0.f, 0.f, 0.f};
      st[jt] = __builtin_amdgcn_mfma_f32_16x16x32_bf16(ka0, q0, st[jt], 0, 0, 0);
      st[jt] = __builtin_amdgcn_mfma_f32_16x16x32_bf16(ka1, q1, st[jt], 0, 0, 0);
    }
    __builtin_amdgcn_s_setprio(0);

    if (tb) {
      const int4* mp = reinterpret_cast<const int4*>(maskb + j0);
#pragma unroll
      for (int jt = 0; jt < 4; ++jt) {
        const int4 mv = mp[(jt >> 1) * 8 + quad * 2 + (jt & 1)];
        if (mv.x == 0) st[jt][0] = -1e30f;
        if (mv.y == 0) st[jt][1] = -1e30f;
        if (mv.z == 0) st[jt][2] = -1e30f;
        if (mv.w == 0) st[jt][3] = -1e30f;
      }
    }
    if (jc == ib) {  // diagonal tile (only reachable when jhi == ib)
#pragma unroll
      for (int jt = 0; jt < 4; ++jt) {
        const int jb = j0 + (jt >> 1) * 32 + quad * 8 + (jt & 1) * 4;
#pragma unroll
        for (int r = 0; r < 4; ++r)
          if (jb + r > ir) st[jt][r] = -1e30f;
      }
    }

    float tmax = -1e30f;
#pragma unroll
    for (int jt = 0; jt < 4; ++jt)
#pragma unroll
      for (int r = 0; r < 4; ++r) tmax = fmaxf(tmax, st[jt][r]);
    tmax = fmaxf(tmax, __shfl_xor(tmax, 16));
    {
      uix2 rr = __builtin_amdgcn_permlane32_swap(__float_as_uint(tmax),
                                                 __float_as_uint(tmax), false, false);
      tmax = fmaxf(__uint_as_float(rr.x), __uint_as_float(rr.y));
    }
    if (jc == jlo) mr = fmaxf(tmax, -1e20f);  // synchronous seed

    unsigned int pw[8];
#pragma unroll
    for (int jt = 0; jt < 4; ++jt) {
      float p0 = __builtin_amdgcn_exp2f(fminf(st[jt][0] - mr, 60.f));
      float p1 = __builtin_amdgcn_exp2f(fminf(st[jt][1] - mr, 60.f));
      float p2 = __builtin_amdgcn_exp2f(fminf(st[jt][2] - mr, 60.f));
      float p3 = __builtin_amdgcn_exp2f(fminf(st[jt][3] - mr, 60.f));
      lq += (p0 + p1) + (p2 + p3);
      pw[2 * jt] = pk2bf(p0, p1);
      pw[2 * jt + 1] = pk2bf(p2, p3);
    }
    const bf16x8 pa0 = __builtin_bit_cast(bf16x8, uix4{pw[0], pw[1], pw[2], pw[3]});
    const bf16x8 pa1 = __builtin_bit_cast(bf16x8, uix4{pw[4], pw[5], pw[6], pw[7]});

    __builtin_amdgcn_s_setprio(1);
#pragma unroll
    for (int vt = 0; vt < 4; ++vt) {
      bf16x8 vb0 = *reinterpret_cast<const bf16x8*>(&Vcur[(vt * 16 + fr) * 64 + cA0]);
      bf16x8 vb1 = *reinterpret_cast<const bf16x8*>(&Vcur[(vt * 16 + fr) * 64 + cA1]);
      o[vt] = __builtin_amdgcn_mfma_f32_16x16x32_bf16(vb0, pa0, o[vt], 0, 0, 0);
      o[vt] = __builtin_amdgcn_mfma_f32_16x16x32_bf16(vb1, pa1, o[vt], 0, 0, 0);
    }
    __builtin_amdgcn_s_setprio(0);

    if (jc > jlo) {  // deferred (threshold-8) max update, post-PV
      const bool upd = __ballot(tmax > mr + 8.f) != 0ull;
      if (upd) {
        const float mn = fmaxf(mr, tmax);
        const float corr = __builtin_amdgcn_exp2f(mr - mn);
        mr = mn;
        lq *= corr;
#pragma unroll
        for (int vt = 0; vt < 4; ++vt) {
          o[vt][0] *= corr; o[vt][1] *= corr; o[vt][2] *= corr; o[vt][3] *= corr;
        }
      }
    }
  }

  float lr = lq;
  lr += __shfl_xor(lr, 16);
  lr += __shfl_xor(lr, 32);

  if (hf < 0) {  // unsplit: normalize + store to concat
    const float inv = (padi != 0 && lr > 0.f) ? 1.f / lr : 0.f;
    unsigned short* orow = concat + ((size_t)(b * SEQ + ir)) * DMODEL + h * HD;
#pragma unroll
    for (int vt = 0; vt < 4; ++vt) {
      uint2 pk;
      pk.x = pk2bf(o[vt][0] * inv, o[vt][1] * inv);
      pk.y = pk2bf(o[vt][2] * inv, o[vt][3] * inv);
      *reinterpret_cast<uint2*>(orow + vt * 16 + quad * 4) = pk;
    }
  } else {  // split half: raw partial (o unnormalized, m, l) to workspace
    const int entry = (bh * 12 + (ib - 20)) * 2 + hf;
    float* po = part_o + ((size_t)entry * 64 + (wave * 16 + fr)) * 64;
#pragma unroll
    for (int vt = 0; vt < 4; ++vt)
      *reinterpret_cast<f32x4*>(po + vt * 16 + quad * 4) = o[vt];
    if (quad == 0) {  // m,l replicated across quads; one writer per row
      float* pml = part_ml + (size_t)entry * 128;
      pml[wave * 16 + fr] = mr;
      pml[64 + wave * 16 + fr] = lr;
    }
  }
}

// merge the two j-halves of each split (bh, ib): o = (o1*c1 + o2*c2)/l,
// c_i = exp2(m_i - max(m1,m2)), l = l1*c1 + l2*c2. 384 blocks x 256 thr;
// thread = (row = tid>>2, 16-col group = tid&3).
__global__ __launch_bounds__(256) void attn_combine_kernel(
    const float* __restrict__ part_o, const float* __restrict__ part_ml,
    const int* __restrict__ mask, unsigned short* __restrict__ concat) {
  const int bx = blockIdx.x;
  const int bh = bx / 12, q = bx % 12;
  const int ib = 20 + q;
  const int b = bh >> 4, h = bh & 15;
  const int r = threadIdx.x >> 2, cg = threadIdx.x & 3;
  const int e0 = (bh * 12 + q) * 2;
  const float m1 = part_ml[(size_t)e0 * 128 + r];
  const float l1 = part_ml[(size_t)e0 * 128 + 64 + r];
  const float m2 = part_ml[(size_t)(e0 + 1) * 128 + r];
  const float l2 = part_ml[(size_t)(e0 + 1) * 128 + 64 + r];
  const float m = fmaxf(m1, m2);
  const float c1 = __builtin_amdgcn_exp2f(m1 - m);
  const float c2 = __builtin_amdgcn_exp2f(m2 - m);
  const float l = l1 * c1 + l2 * c2;
  const int i = ib * 64 + r;
  const int padi = mask[b * SEQ + i];
  const float inv = (padi != 0 && l > 0.f) ? 1.f / l : 0.f;
  const float s1 = c1 * inv, s2 = c2 * inv;
  const float* po1 = part_o + ((size_t)e0 * 64 + r) * 64 + cg * 16;
  const float* po2 = part_o + ((size_t)(e0 + 1) * 64 + r) * 64 + cg * 16;
  unsigned int wb[8];
#pragma unroll
  for (int v = 0; v < 4; ++v) {
    f32x4 a = *reinterpret_cast<const f32x4*>(po1 + v * 4);
    f32x4 c = *reinterpret_cast<const f32x4*>(po2 + v * 4);
    wb[2 * v] = pk2bf(a[0] * s1 + c[0] * s2, a[1] * s1 + c[1] * s2);
    wb[2 * v + 1] = pk2bf(a[2] * s1 + c[2] * s2, a[3] * s1 + c[3] * s2);
  }
  unsigned short* dst = concat + ((size_t)(b * SEQ + i)) * DMODEL + h * HD + cg * 16;
  reinterpret_cast<uint4*>(dst)[0] = uint4{wb[0], wb[1], wb[2], wb[3]};
  reinterpret_cast<uint4*>(dst)[1] = uint4{wb[4], wb[5], wb[6], wb[7]};
}

extern "C" void kernel_launch(void* const* d_in, const int* in_sizes, int n_in,
                              void* d_out, int out_size, void* d_ws, size_t ws_size,
                              hipStream_t stream) {
  (void)in_sizes; (void)n_in; (void)out_size;
  const float* x  = (const float*)d_in[0];
  const int* mask = (const int*)d_in[1];
  const float* Wq = (const float*)d_in[2];
  const float* bq = (const float*)d_in[3];
  const float* Wk = (const float*)d_in[4];
  const float* bk = (const float*)d_in[5];
  const float* Wv = (const float*)d_in[6];
  const float* bv = (const float*)d_in[7];
  const float* Wo = (const float*)d_in[8];
  const float* bo = (const float*)d_in[9];
  float* out = (float*)d_out;

  char* ws = (char*)d_ws;
  if (ws_size < (48ull << 20)) return;
  unsigned short* xb  = (unsigned short*)(ws);                 // 8 MB x bf16 [4096][1024]
  unsigned short* wqb = (unsigned short*)(ws + (8ull  << 20)); // wq|wk|wv contiguous ->
  unsigned short* wkb = (unsigned short*)(ws + (10ull << 20)); //   [3072][1024] B matrix
  unsigned short* wvb = (unsigned short*)(ws + (12ull << 20));
  unsigned short* wob = (unsigned short*)(ws + (14ull << 20));
  unsigned short* Qb  = (unsigned short*)(ws + (16ull << 20)); // 8 MB [b,h,s,64] (xscale)
  unsigned short* Kb  = (unsigned short*)(ws + (24ull << 20)); // 8 MB [b,h,s,64]
  unsigned short* Vtb = (unsigned short*)(ws + (32ull << 20)); // 8 MB [b,h,64,s]
  unsigned short* cb  = (unsigned short*)(ws + (40ull << 20)); // 8 MB concat bf16
  // attn partials overlay the xb/wqb/wkb/wvb region (dead after gemm0):
  float* part_o  = (float*)(ws);                // 768 x 64 x 64 f32 = 12.6 MB
  float* part_ml = (float*)(ws + (13ull << 20)); // 768 x 2 x 64 f32 = 0.4 MB

  cast_all_kernel<<<4096, 256, 0, stream>>>(x, Wq, Wk, Wv, Wo, xb, wqb, wkb, wvb, wob);

  // fused QKV projection (2-phase dbuf 128^2): B = [wq;wk;wv] = [3072][1024]
  gemm128<0, 128><<<dim3(24, 32), 256, 0, stream>>>(xb, wqb, bq, bk, bv,
                                                    nullptr, Qb, Kb, Vtb, 1024);

  // flash attention with LPT-ordered split tail (44 units x 32 bh)
  attn_mfma_kernel<<<1408, 256, 0, stream>>>(Qb, Kb, Vtb, mask, cb, part_o, part_ml);
  attn_combine_kernel<<<384, 256, 0, stream>>>(part_o, part_ml, mask, cb);

  // out projection: 64-row M-tiles -> 512 blocks (2/CU)
  gemm128<1, 64><<<dim3(8, 64), 256, 0, stream>>>(cb, wob, bo, nullptr, nullptr,
                                                  out, nullptr, nullptr, nullptr, 1024);
}